// Round 2
// baseline (1810.686 us; speedup 1.0000x reference)
//
#include <hip/hip_runtime.h>
#include <math.h>

#define DIM 4096
#define HIDDEN 11008
#define NB 32          // batch
#define EPS 1e-5f

// ---------------- RMSNorm, writes transposed (K x 32) ----------------
__global__ __launch_bounds__(256) void rmsnorm_t_kernel(
    const float* __restrict__ x, const float* __restrict__ w,
    float* __restrict__ outT)
{
  int m = blockIdx.x;           // 0..31
  int tid = threadIdx.x;
  const float4* xr = (const float4*)(x + (size_t)m * DIM);
  const float4* wr = (const float4*)w;
  float4 xv[4];
  float s = 0.f;
#pragma unroll
  for (int i = 0; i < 4; i++) {
    xv[i] = xr[tid + i * 256];
    s += xv[i].x * xv[i].x + xv[i].y * xv[i].y + xv[i].z * xv[i].z + xv[i].w * xv[i].w;
  }
#pragma unroll
  for (int off = 32; off > 0; off >>= 1) s += __shfl_down(s, off, 64);
  __shared__ float wsum[4];
  if ((tid & 63) == 0) wsum[tid >> 6] = s;
  __syncthreads();
  float tot = wsum[0] + wsum[1] + wsum[2] + wsum[3];
  float scale = 1.0f / (sqrtf(tot / (float)DIM) + EPS);
#pragma unroll
  for (int i = 0; i < 4; i++) {
    float4 wv = wr[tid + i * 256];
    int k = (tid + i * 256) * 4;
    outT[(size_t)(k + 0) * NB + m] = xv[i].x * wv.x * scale;
    outT[(size_t)(k + 1) * NB + m] = xv[i].y * wv.y * scale;
    outT[(size_t)(k + 2) * NB + m] = xv[i].z * wv.z * scale;
    outT[(size_t)(k + 3) * NB + m] = xv[i].w * wv.w * scale;
  }
}

// ---------------- skinny GEMM, LDS-free ----------------
// C(32 x ldc) += AT(K x 32)^T * W(K x ldw).  A rows are wave-uniform -> scalar
// loads (SGPR operand in FMA). W streamed with coalesced dwordx2, 8-deep
// ping-pong register prefetch. Split-K combined via fp32 atomicAdd.
// blockIdx.z selects (W0,colOff0) or (W1,colOff1) so two GEMMs sharing A fuse
// into one launch.
__global__ __launch_bounds__(256) void gemm32s_kernel(
    const float* __restrict__ AT,
    const float* __restrict__ W0, const float* __restrict__ W1,
    float* __restrict__ C, int ldw, int ldc, int colOff0, int colOff1,
    int K, int kPerBlk)
{
  const float* W = blockIdx.z ? W1 : W0;
  int colOff = blockIdx.z ? colOff1 : colOff0;
  int tid = threadIdx.x;
  int col = blockIdx.x * 512 + tid * 2;
  bool active = (col < ldw);
  int k0 = blockIdx.y * kPerBlk;
  int kEnd = k0 + kPerBlk; if (kEnd > K) kEnd = K;

  float acc0[32], acc1[32];
#pragma unroll
  for (int r = 0; r < 32; r++) { acc0[r] = 0.f; acc1[r] = 0.f; }

  float2 bufA[8], bufB[8];

#define LOADW(buf, kb)                                                        \
  {                                                                           \
    _Pragma("unroll")                                                         \
    for (int u = 0; u < 8; u++) {                                             \
      int kk = (kb) + u;                                                      \
      buf[u] = (active && kk < kEnd)                                          \
                   ? *(const float2*)&W[(size_t)kk * ldw + col]               \
                   : make_float2(0.f, 0.f);                                   \
    }                                                                         \
  }

#define COMP(buf, kb)                                                         \
  {                                                                           \
    _Pragma("unroll")                                                         \
    for (int u = 0; u < 8; u++) {                                             \
      int kk = (kb) + u; if (kk > K - 1) kk = K - 1;                          \
      const float* ar = AT + (size_t)kk * NB;                                 \
      _Pragma("unroll")                                                       \
      for (int r = 0; r < 32; r++) {                                          \
        float a = ar[r];                                                      \
        acc0[r] += a * buf[u].x;                                              \
        acc1[r] += a * buf[u].y;                                              \
      }                                                                       \
    }                                                                         \
  }

  LOADW(bufA, k0);
  for (int k = k0; k < kEnd; k += 16) {
    LOADW(bufB, k + 8);
    COMP(bufA, k);
    LOADW(bufA, k + 16);
    COMP(bufB, k + 8);
  }
#undef LOADW
#undef COMP

  if (active) {
    float* cb = C + colOff + col;
#pragma unroll
    for (int r = 0; r < 32; r++) {
      atomicAdd(cb + (size_t)r * ldc,     acc0[r]);
      atomicAdd(cb + (size_t)r * ldc + 1, acc1[r]);
    }
  }
}

// ---------------- RoPE in place on q (32 heads) and k (8 heads) ----------------
__global__ __launch_bounds__(256) void rope_kernel(
    float* __restrict__ qkv, const float* __restrict__ cosv, const float* __restrict__ sinv)
{
  int idx = blockIdx.x * 256 + threadIdx.x;   // 32 * 40 * 64
  int j = idx & 63;
  int h = (idx >> 6) % 40;
  int b = idx / (64 * 40);
  int col = (h < 32) ? (h * 128 + 2 * j) : (DIM + (h - 32) * 128 + 2 * j);
  float* p = qkv + (size_t)b * 6144 + col;
  float c = cosv[j], s = sinv[j];
  float x0 = p[0], x1 = p[1];
  p[0] = x0 * c - x1 * s;
  p[1] = x0 * s + x1 * c;
}

// ---------------- attention: one block per (b, kv-head g); L = 1025 ----------------
#define KVP 132          // padded K/V row stride (floats), 16B-aligned, conflict-free
#define SCP 1028         // padded score row stride
__global__ __launch_bounds__(256) void attn_kernel(
    const float* __restrict__ qkv,
    const float* __restrict__ ck, const float* __restrict__ cv,
    float* __restrict__ attnoT)
{
  __shared__ float qs[4 * 128];
  __shared__ float sc[4 * SCP];
  __shared__ float kvt[64 * KVP];
  __shared__ float invs[4];
  int tid = threadIdx.x;
  int b = blockIdx.x >> 3, g = blockIdx.x & 7;
  const float scale = 0.08838834764831845f;   // 1/sqrt(128)

  for (int i = tid; i < 512; i += 256)
    qs[i] = qkv[(size_t)b * 6144 + (size_t)g * 512 + i];

  const float* kbase = ck + (((size_t)b * 2048) * 8 + g) * 128;   // row stride 1024 floats
  float4 pre[8];

#pragma unroll
  for (int i = 0; i < 8; i++) {
    int e = tid + i * 256;
    int row = e >> 5, c = (e & 31) << 2;
    pre[i] = *(const float4*)&kbase[(size_t)row * 1024 + c];
  }
#pragma unroll
  for (int i = 0; i < 8; i++) {
    int e = tid + i * 256;
    int row = e >> 5, c = (e & 31) << 2;
    *(float4*)&kvt[row * KVP + c] = pre[i];
  }
  __syncthreads();

  int r1 = tid >> 6, l1 = tid & 63;
  for (int t = 0; t < 16; t++) {
    if (t < 15) {
      int l0 = (t + 1) * 64;
#pragma unroll
      for (int i = 0; i < 8; i++) {
        int e = tid + i * 256;
        int row = e >> 5, c = (e & 31) << 2;
        pre[i] = *(const float4*)&kbase[(size_t)(l0 + row) * 1024 + c];
      }
    }
    float a = 0.f;
    const float4* kr = (const float4*)&kvt[l1 * KVP];
    const float4* qr = (const float4*)&qs[r1 * 128];
#pragma unroll
    for (int d = 0; d < 32; d++) {
      float4 kv = kr[d], qv = qr[d];
      a += qv.x * kv.x + qv.y * kv.y + qv.z * kv.z + qv.w * kv.w;
    }
    sc[r1 * SCP + t * 64 + l1] = a * scale;
    __syncthreads();
    if (t < 15) {
#pragma unroll
      for (int i = 0; i < 8; i++) {
        int e = tid + i * 256;
        int row = e >> 5, c = (e & 31) << 2;
        *(float4*)&kvt[row * KVP + c] = pre[i];
      }
      __syncthreads();
    }
  }

  // tail score: l = 1024 uses fresh roped k from qkv
  {
    const float* kn = qkv + (size_t)b * 6144 + DIM + (size_t)g * 128;
    float part = qs[r1 * 128 + l1] * kn[l1] + qs[r1 * 128 + 64 + l1] * kn[64 + l1];
#pragma unroll
    for (int off = 32; off > 0; off >>= 1) part += __shfl_down(part, off, 64);
    if (l1 == 0) sc[r1 * SCP + 1024] = part * scale;
  }
  __syncthreads();

  // softmax: wave r1 owns row r1
  {
    float m = -1e30f;
    for (int l = l1; l < 1025; l += 64) m = fmaxf(m, sc[r1 * SCP + l]);
#pragma unroll
    for (int off = 32; off > 0; off >>= 1) m = fmaxf(m, __shfl_xor(m, off, 64));
    float ssum = 0.f;
    for (int l = l1; l < 1025; l += 64) {
      float e = __expf(sc[r1 * SCP + l] - m);
      sc[r1 * SCP + l] = e;
      ssum += e;
    }
#pragma unroll
    for (int off = 32; off > 0; off >>= 1) ssum += __shfl_xor(ssum, off, 64);
    if (l1 == 0) invs[r1] = 1.0f / ssum;
  }
  __syncthreads();

  // V phase
  const float* vbase = cv + (((size_t)b * 2048) * 8 + g) * 128;
#pragma unroll
  for (int i = 0; i < 8; i++) {
    int e = tid + i * 256;
    int row = e >> 5, c = (e & 31) << 2;
    pre[i] = *(const float4*)&vbase[(size_t)row * 1024 + c];
  }
#pragma unroll
  for (int i = 0; i < 8; i++) {
    int e = tid + i * 256;
    int row = e >> 5, c = (e & 31) << 2;
    *(float4*)&kvt[row * KVP + c] = pre[i];
  }
  __syncthreads();

  int dd = tid & 127, rr = tid >> 7;      // rows rr and rr+2
  float a0 = 0.f, a1 = 0.f;
  for (int t = 0; t < 16; t++) {
    if (t < 15) {
      int l0 = (t + 1) * 64;
#pragma unroll
      for (int i = 0; i < 8; i++) {
        int e = tid + i * 256;
        int row = e >> 5, c = (e & 31) << 2;
        pre[i] = *(const float4*)&vbase[(size_t)(l0 + row) * 1024 + c];
      }
    }
    const float4* p0 = (const float4*)&sc[rr * SCP + t * 64];
    const float4* p1 = (const float4*)&sc[(rr + 2) * SCP + t * 64];
#pragma unroll
    for (int l4 = 0; l4 < 16; l4++) {
      float4 q0 = p0[l4], q1 = p1[l4];
      int lb = l4 * 4;
      float v0 = kvt[(lb + 0) * KVP + dd];
      float v1 = kvt[(lb + 1) * KVP + dd];
      float v2 = kvt[(lb + 2) * KVP + dd];
      float v3 = kvt[(lb + 3) * KVP + dd];
      a0 += q0.x * v0 + q0.y * v1 + q0.z * v2 + q0.w * v3;
      a1 += q1.x * v0 + q1.y * v1 + q1.z * v2 + q1.w * v3;
    }
    __syncthreads();
    if (t < 15) {
#pragma unroll
      for (int i = 0; i < 8; i++) {
        int e = tid + i * 256;
        int row = e >> 5, c = (e & 31) << 2;
        *(float4*)&kvt[row * KVP + c] = pre[i];
      }
      __syncthreads();
    }
  }
  // tail l = 1024: fresh v from qkv
  {
    const float* vn = qkv + (size_t)b * 6144 + DIM + 1024 + (size_t)g * 128;
    float v = vn[dd];
    a0 += sc[rr * SCP + 1024] * v;
    a1 += sc[(rr + 2) * SCP + 1024] * v;
  }
  float i0 = invs[rr], i1 = invs[rr + 2];
  attnoT[(size_t)((g * 4 + rr) * 128 + dd) * NB + b] = a0 * i0;
  attnoT[(size_t)((g * 4 + rr + 2) * 128 + dd) * NB + b] = a1 * i1;
}

// ---------------- SwiGLU elementwise, writes transposed (HIDDEN x 32) ----------------
__global__ __launch_bounds__(256) void silu_kernel(
    const float* __restrict__ gu, float* __restrict__ actT)
{
  int idx = blockIdx.x * 256 + threadIdx.x;   // 11008*32, idx = j*32+m
  int j = idx >> 5, m = idx & 31;
  float g = gu[(size_t)m * 22016 + j];
  float u = gu[(size_t)m * 22016 + HIDDEN + j];
  float sg = g / (1.0f + __expf(-g));
  actT[idx] = sg * u;
}

// ---------------- float4 copy ----------------
__global__ __launch_bounds__(256) void copy4_kernel(
    float* __restrict__ dst, const float* __restrict__ src)
{
  int idx = blockIdx.x * 256 + threadIdx.x;
  ((float4*)dst)[idx] = ((const float4*)src)[idx];
}

extern "C" void kernel_launch(void* const* d_in, const int* in_sizes, int n_in,
                              void* d_out, int out_size, void* d_ws, size_t ws_size,
                              hipStream_t stream)
{
  const float* x   = (const float*)d_in[0];
  // d_in[1] = start_pos (always 1024, compile-time constant here)
  const float* fc  = (const float*)d_in[2];
  const float* fs  = (const float*)d_in[3];
  const float* ck  = (const float*)d_in[4];
  const float* cv  = (const float*)d_in[5];
  const float* wq  = (const float*)d_in[6];
  const float* wk  = (const float*)d_in[7];
  const float* wv  = (const float*)d_in[8];
  const float* wo  = (const float*)d_in[9];
  const float* w1  = (const float*)d_in[10];
  const float* w2  = (const float*)d_in[11];
  const float* w3  = (const float*)d_in[12];
  const float* anw = (const float*)d_in[13];
  const float* fnw = (const float*)d_in[14];
  float* out = (float*)d_out;

  float* ws     = (float*)d_ws;
  float* qkv    = ws;                  // 32 x 6144          (196608)
  float* gateup = ws + 196608;         // 32 x 22016         (704512)
  float* hT     = ws + 901120;         // 4096 x 32          (131072)
  float* out1   = ws + 1032192;        // 32 x 4096          (131072)
  float* h2T    = ws + 1163264;        // 4096 x 32          (131072)
  float* actT   = ws + 1294336;        // 11008 x 32         (352256)
  float* attnoT = ws + 1646592;        // 4096 x 32          (131072)

  // zero the atomic-accumulated buffers (qkv + gateup are adjacent)
  hipMemsetAsync(qkv, 0, (size_t)(196608 + 704512) * sizeof(float), stream);

  // h = rmsnorm(x) -> transposed
  rmsnorm_t_kernel<<<32, 256, 0, stream>>>(x, anw, hT);

  // q projection: 32x4096 cols of qkv
  gemm32s_kernel<<<dim3(8, 32, 1), 256, 0, stream>>>(hT, wq, wq, qkv, 4096, 6144, 0, 0, 4096, 128);
  // k,v projections fused via grid.z
  gemm32s_kernel<<<dim3(2, 64, 2), 256, 0, stream>>>(hT, wk, wv, qkv, 1024, 6144, 4096, 5120, 4096, 64);

  // rope on q,k (position 1024)
  rope_kernel<<<320, 256, 0, stream>>>(qkv, fc, fs);

  // attention over 1024 cached + 1 fresh position
  attn_kernel<<<256, 256, 0, stream>>>(qkv, ck, cv, attnoT);

  // out1 = x + attn_out @ wo
  copy4_kernel<<<128, 256, 0, stream>>>(out1, x);
  gemm32s_kernel<<<dim3(8, 32, 1), 256, 0, stream>>>(attnoT, wo, wo, out1, 4096, 4096, 0, 0, 4096, 128);

  // h2 = rmsnorm(out1)
  rmsnorm_t_kernel<<<32, 256, 0, stream>>>(out1, fnw, h2T);

  // gate/up projections fused via grid.z (22*512 = 11264 > 11008: col guard)
  gemm32s_kernel<<<dim3(22, 8, 2), 256, 0, stream>>>(h2T, w1, w3, gateup, 11008, 22016, 0, 11008, 4096, 512);

  // act = silu(gate) * up  -> transposed
  silu_kernel<<<1376, 256, 0, stream>>>(gateup, actT);

  // out = out1 + act @ w2
  copy4_kernel<<<128, 256, 0, stream>>>(out, out1);
  gemm32s_kernel<<<dim3(8, 32, 1), 256, 0, stream>>>(actT, w2, w2, out, 4096, 4096, 0, 0, 11008, 344);
}